// Round 6
// baseline (306.293 us; speedup 1.0000x reference)
//
#include <hip/hip_runtime.h>

#define H 20
#define NODE 480
#define BATCH 16384
#define BLK 256
#define GPT 4   // nodes per thread: out/in become 16B-per-lane (quarter-line), L3 merges

typedef float v2f __attribute__((ext_vector_type(2)));
typedef float v4f __attribute__((ext_vector_type(4)));

// tanh(x) = 1 - 2/(e^{2x}+1); 2 trans + 3 VALU, saturates correctly at +-inf.
__device__ __forceinline__ float fast_tanh(float x) {
    float t = __builtin_amdgcn_exp2f(x * 2.8853900817779268f); // e^{2x}
    return 1.0f - 2.0f * __builtin_amdgcn_rcpf(t + 1.0f);
}
__device__ __forceinline__ v2f tanh2(v2f v) {
    v2f r; r.x = fast_tanh(v.x); r.y = fast_tanh(v.y); return r;
}

// Fused: 4 nodes per thread, no transpose kernels. g is block-uniform inside
// each unrolled gi iteration -> weights stay wave-uniform s_loads.
// amdgpu_waves_per_eu(1,5): 102-VGPR budget so h2+a2 (40 floats) + io (8) live
// cleanly in arch VGPRs (R2/R4 showed allocator capping at 24/32 -> AGPR moves).
__global__ __attribute__((amdgpu_flat_work_group_size(BLK, BLK),
                          amdgpu_waves_per_eu(1, 5)))
void mlp480_fused(
    const float* __restrict__ inputs,
    const float* __restrict__ W1, const float* __restrict__ b1,
    const float* __restrict__ W2, const float* __restrict__ b2,
    const float* __restrict__ W3, const float* __restrict__ b3,
    const float* __restrict__ W4, const float* __restrict__ b4,
    float* __restrict__ out)
{
    const int g0 = blockIdx.x * GPT;
    const int b  = blockIdx.y * BLK + threadIdx.x;
    const size_t rowoff = (size_t)b * NODE + g0;   // 16B-aligned (g0 % 4 == 0)

    const v4f xv = *(const v4f*)(inputs + rowoff);
    const float xs[GPT] = {xv.x, xv.y, xv.z, xv.w};
    float os[GPT];

#pragma unroll
    for (int gi = 0; gi < GPT; ++gi) {          // fully unrolled: all idx static
        const int g = g0 + gi;

        const v2f* __restrict__ w1v = (const v2f*)(W1 + g * H);
        const v2f* __restrict__ b1v = (const v2f*)(b1 + g * H);
        const v2f* __restrict__ b2v = (const v2f*)(b2 + g * H);
        const v2f* __restrict__ b3v = (const v2f*)(b3 + g * H);
        const v2f* __restrict__ w4v = (const v2f*)(W4 + g * H);
        const float* __restrict__ w2 = W2 + g * H * H;
        const float* __restrict__ w3 = W3 + g * H * H;
        const float bias4 = b4[g];

        const float x = xs[gi];
        const v2f x2 = {x, x};

        v2f h2[10], a2[10];

        // Layer 1: Linear(1,H) + tanh (10 pk_fma)
#pragma unroll
        for (int j = 0; j < 10; ++j)
            h2[j] = tanh2(x2 * w1v[j] + b1v[j]);

        // Layer 2: k-outer, contiguous wave-uniform rows (200 pk_fma)
#pragma unroll
        for (int l = 0; l < 10; ++l) a2[l] = b2v[l];
#pragma unroll
        for (int k = 0; k < H; ++k) {
            const float hk = (k & 1) ? h2[k >> 1].y : h2[k >> 1].x;
            const v2f hk2 = {hk, hk};
            const v2f* __restrict__ row = (const v2f*)(w2 + k * H);
#pragma unroll
            for (int l = 0; l < 10; ++l) a2[l] = hk2 * row[l] + a2[l];
        }
#pragma unroll
        for (int l = 0; l < 10; ++l) h2[l] = tanh2(a2[l]);

        // Layer 3
#pragma unroll
        for (int l = 0; l < 10; ++l) a2[l] = b3v[l];
#pragma unroll
        for (int k = 0; k < H; ++k) {
            const float hk = (k & 1) ? h2[k >> 1].y : h2[k >> 1].x;
            const v2f hk2 = {hk, hk};
            const v2f* __restrict__ row = (const v2f*)(w3 + k * H);
#pragma unroll
            for (int l = 0; l < 10; ++l) a2[l] = hk2 * row[l] + a2[l];
        }
#pragma unroll
        for (int l = 0; l < 10; ++l) h2[l] = tanh2(a2[l]);

        // Layer 4: Linear(H,1)
        v2f s2 = {bias4, 0.0f};
#pragma unroll
        for (int k = 0; k < 10; ++k) s2 = h2[k] * w4v[k] + s2;
        os[gi] = s2.x + s2.y;
    }

    v4f ov = {os[0], os[1], os[2], os[3]};
    *(v4f*)(out + rowoff) = ov;
}

extern "C" void kernel_launch(void* const* d_in, const int* in_sizes, int n_in,
                              void* d_out, int out_size, void* d_ws, size_t ws_size,
                              hipStream_t stream) {
    const float* inputs = (const float*)d_in[0];
    const float* W1 = (const float*)d_in[1];
    const float* b1 = (const float*)d_in[2];
    const float* W2 = (const float*)d_in[3];
    const float* b2 = (const float*)d_in[4];
    const float* W3 = (const float*)d_in[5];
    const float* b3 = (const float*)d_in[6];
    const float* W4 = (const float*)d_in[7];
    const float* b4 = (const float*)d_in[8];
    float* out = (float*)d_out;

    dim3 grid(NODE / GPT, BATCH / BLK);   // (120, 64)
    mlp480_fused<<<grid, BLK, 0, stream>>>(inputs, W1, b1, W2, b2,
                                           W3, b3, W4, b4, out);
}